// Round 1
// baseline (446.773 us; speedup 1.0000x reference)
//
#include <hip/hip_runtime.h>

// cummax along Ts (axis 2) of x[B=8, Tt=128, Ts=128, C=512] fp32.
//
// Wave-per-stripe sequential scan, barrier-free:
//   task = (row, half-C), row in [0,1024), half in {0,1}  -> 2048 tasks.
//   One wave (64 lanes) owns one task; lane l owns float4 column
//   cv = half*64 + l. The wave walks Ts in 8 chunks of 16, keeping a
//   running carry in registers. Chunks are double-buffered (a/b) so the
//   next chunk's 16 KB of loads are in flight under the current chunk's
//   prefix-max + stores. No LDS, no __syncthreads, no vmcnt(0) drain.
//
// Grid: 512 blocks x 256 threads = 2048 waves = exactly 2 blocks/CU,
// single dispatch round, perfectly balanced.

constexpr int TS     = 128;
constexpr int CV     = 128;          // C/4 float4 per (row, s) line
constexpr int CHUNK  = 16;           // s-steps per chunk
constexpr int NCHUNK = TS / CHUNK;   // 8

typedef float nativef4 __attribute__((ext_vector_type(4)));

__device__ __forceinline__ float4 fmax4(float4 a, float4 b) {
  return make_float4(fmaxf(a.x, b.x), fmaxf(a.y, b.y),
                     fmaxf(a.z, b.z), fmaxf(a.w, b.w));
}

__device__ __forceinline__ void nt_store(float4* dst, float4 v) {
  __builtin_nontemporal_store(*reinterpret_cast<nativef4*>(&v),
                              reinterpret_cast<nativef4*>(dst));
}

// CH is compile-time so every register-array index is constant (no scratch).
template <int CH>
__device__ __forceinline__ void load_chunk(float4 (&buf)[CHUNK],
                                           const float4* __restrict__ p) {
#pragma unroll
  for (int i = 0; i < CHUNK; ++i)
    buf[i] = p[(size_t)(CH * CHUNK + i) * CV];
}

template <int CH>
__device__ __forceinline__ void scan_store_chunk(float4 (&buf)[CHUNK],
                                                 float4& carry,
                                                 float4* __restrict__ q) {
  buf[0] = fmax4(buf[0], carry);
#pragma unroll
  for (int i = 1; i < CHUNK; ++i) buf[i] = fmax4(buf[i], buf[i - 1]);
#pragma unroll
  for (int i = 0; i < CHUNK; ++i)
    nt_store(&q[(size_t)(CH * CHUNK + i) * CV], buf[i]);
  carry = buf[CHUNK - 1];
}

__global__ __launch_bounds__(256, 2) void cummax_scan(
    const float4* __restrict__ x, float4* __restrict__ out) {
  const int tid  = threadIdx.x;
  const int wid  = tid >> 6;                    // wave in block: 0..3
  const int lane = tid & 63;
  const int task = (blockIdx.x << 2) | wid;     // 0..2047
  const int row  = task >> 1;                   // (b, t) flattened
  const int cv   = ((task & 1) << 6) | lane;    // float4 column

  const size_t base = (size_t)row * TS * CV + cv;
  const float4* __restrict__ p = x + base;
  float4*       __restrict__ q = out + base;

  const float ninf = -__builtin_inff();
  float4 carry = make_float4(ninf, ninf, ninf, ninf);

  float4 a[CHUNK], b[CHUNK];

  // Software pipeline: loads for chunk ch+1 issued before processing ch.
  load_chunk<0>(a, p);
  load_chunk<1>(b, p);
  scan_store_chunk<0>(a, carry, q);
  load_chunk<2>(a, p);
  scan_store_chunk<1>(b, carry, q);
  load_chunk<3>(b, p);
  scan_store_chunk<2>(a, carry, q);
  load_chunk<4>(a, p);
  scan_store_chunk<3>(b, carry, q);
  load_chunk<5>(b, p);
  scan_store_chunk<4>(a, carry, q);
  load_chunk<6>(a, p);
  scan_store_chunk<5>(b, carry, q);
  load_chunk<7>(b, p);
  scan_store_chunk<6>(a, carry, q);
  scan_store_chunk<7>(b, carry, q);
}

extern "C" void kernel_launch(void* const* d_in, const int* in_sizes, int n_in,
                              void* d_out, int out_size, void* d_ws, size_t ws_size,
                              hipStream_t stream) {
  const float4* x = (const float4*)d_in[0];
  float4* out = (float4*)d_out;

  // 2048 wave-tasks / 4 waves per block = 512 blocks of 256 threads.
  cummax_scan<<<512, 256, 0, stream>>>(x, out);
}

// Round 2
// 417.195 us; speedup vs baseline: 1.0709x; 1.0709x over previous
//
#include <hip/hip_runtime.h>

// cummax along Ts (axis 2) of x[B=8, Tt=128, Ts=128, C=512] fp32.
//
// Block-scan, occupancy-first variant:
//   block = 1024 threads = 16 s-chunks (wave-uniform: chunk == wave id)
//           x 64 c-quads, covering one (row, half-C) stripe.
//   Per thread: 8 independent float4 nt-loads -> in-register prefix max
//   (chunk of 8 s-steps) -> chunk totals through LDS (one barrier) ->
//   carry = prefix max of preceding chunk totals -> 8 coalesced nt-stores.
//
// CHUNK=8 keeps data regs at 32 VGPR (~50 total) -> under the 64-VGPR
// occupancy cliff -> 32 waves/CU, 2 blocks/CU. Grid = 1024 rows x 2
// half-C = 2048 blocks, exactly one dispatch round of 2 blocks/CU.

constexpr int TS     = 128;
constexpr int CV     = 128;           // C/4 float4 per (row, s) line
constexpr int CHUNK  = 8;             // s-steps per thread
constexpr int NCHUNK = TS / CHUNK;    // 16 chunks == 16 waves
constexpr int CVB    = 64;            // c-quads per block (one wave wide)

typedef float nativef4 __attribute__((ext_vector_type(4)));

__device__ __forceinline__ float4 fmax4(float4 a, float4 b) {
  return make_float4(fmaxf(a.x, b.x), fmaxf(a.y, b.y),
                     fmaxf(a.z, b.z), fmaxf(a.w, b.w));
}

__device__ __forceinline__ float4 nt_load(const float4* src) {
  nativef4 t = __builtin_nontemporal_load(
      reinterpret_cast<const nativef4*>(src));
  return *reinterpret_cast<float4*>(&t);
}

__device__ __forceinline__ void nt_store(float4* dst, float4 v) {
  __builtin_nontemporal_store(*reinterpret_cast<nativef4*>(&v),
                              reinterpret_cast<nativef4*>(dst));
}

__global__ __launch_bounds__(1024) void cummax_scan(
    const float4* __restrict__ x, float4* __restrict__ out) {
  __shared__ float4 totals[NCHUNK][CVB];  // 16 KiB

  const int tid   = threadIdx.x;
  const int chunk = tid >> 6;           // wave index == chunk index
  const int cvl   = tid & 63;
  const int row   = blockIdx.x >> 1;    // (b, t) flattened
  const int cv    = ((blockIdx.x & 1) << 6) | cvl;

  const size_t base = ((size_t)row * TS + (size_t)chunk * CHUNK) * CV + cv;
  const float4* __restrict__ p = x + base;
  float4*       __restrict__ q = out + base;

  // 1) batch-load chunk into registers (8 independent 1 KiB/wave loads)
  float4 v[CHUNK];
#pragma unroll
  for (int i = 0; i < CHUNK; ++i) v[i] = nt_load(p + (size_t)i * CV);

  // 2) in-register prefix max (4 independent chains of 7)
#pragma unroll
  for (int i = 1; i < CHUNK; ++i) v[i] = fmax4(v[i], v[i - 1]);

  // 3) chunk totals -> LDS -> one barrier -> carry
  totals[chunk][cvl] = v[CHUNK - 1];
  __syncthreads();

  const float ninf = -__builtin_inff();
  float4 carry = make_float4(ninf, ninf, ninf, ninf);
  for (int c = 0; c < chunk; ++c) {     // wave-uniform trip count
    carry = fmax4(carry, totals[c][cvl]);
  }

  // 4) apply carry + coalesced nt stores (output never re-read)
#pragma unroll
  for (int i = 0; i < CHUNK; ++i) {
    nt_store(q + (size_t)i * CV, fmax4(carry, v[i]));
  }
}

extern "C" void kernel_launch(void* const* d_in, const int* in_sizes, int n_in,
                              void* d_out, int out_size, void* d_ws, size_t ws_size,
                              hipStream_t stream) {
  const float4* x = (const float4*)d_in[0];
  float4* out = (float4*)d_out;

  // 1024 rows x 2 half-C stripes = 2048 blocks of 1024 threads.
  constexpr int ROWS = 8 * 128;
  cummax_scan<<<ROWS * 2, 1024, 0, stream>>>(x, out);
}